// Round 5
// baseline (287.851 us; speedup 1.0000x reference)
//
#include <hip/hip_runtime.h>

// UpSampling3D x2 trilinear, align_corners=True.
// x [64,48,48,48] f32 -> y [64,96,96,96] f32
// pos(o) = 47*o/95; weights (1-fr, fr) at (floor, floor+1); norm (1/(1+1e-6))^3.
// Note: floor(47*o/95) <= 46 for o<=95, so the +1 neighbor never clamps.
//
// R3 structure: block = 16x16 (r,c) output tile, thread owns a full 96-d line.
//  - 4 bilinear input rows read DIRECTLY from global (L1/L2-resident tile) as
//    compile-time-offset float4 windows; no input LDS, no barriers.
//  - rc-blend factored once per input float (f[]), then 2 FMA per output.
//  - wave-local XOR-swizzled transpose staging (32 KB) -> coalesced stores.

#define IN_N   48
#define RS_IN  (48*48)
#define BH_IN  (48*48*48)
#define OUT_N  96
#define RS_OUT (96*96)
#define BH_OUT (96*96*96)

__global__ __launch_bounds__(256, 4) void up3d_kernel(const float* __restrict__ x,
                                                      float* __restrict__ y) {
    __shared__ float res[4 * 64 * 32];   // 32 KB: per-wave 64 rows x 32 floats (XOR-swizzled)

    const int tid  = threadIdx.x;
    const int wave = tid >> 6;
    const int lane = tid & 63;
    const int bc = blockIdx.x, br = blockIdx.y, bh = blockIdx.z;

    const int r_loc = tid >> 4;          // 0..15  (wave w -> rows 4w..4w+3)
    const int c_loc = tid & 15;
    const int r_out = br * 16 + r_loc;
    const int c_out = bc * 16 + c_loc;

    const int r0 = (47 * r_out) / 95;
    const int c0 = (47 * c_out) / 95;
    const float wr1 = (float)((47 * r_out) % 95) * (1.0f / 95.0f);
    const float wc1 = (float)((47 * c_out) % 95) * (1.0f / 95.0f);
    const float wr0 = 1.0f - wr1, wc0 = 1.0f - wc1;

    const float n1 = 1.0f / (1.0f + 1e-6f);
    const float norm = n1 * n1 * n1;
    const float w00 = wr0 * wc0 * norm, w01 = wr0 * wc1 * norm;
    const float w10 = wr1 * wc0 * norm, w11 = wr1 * wc1 * norm;

    const float* p00 = x + (size_t)bh * BH_IN + r0 * RS_IN + c0 * IN_N;
    const float* p01 = p00 + IN_N;       // (r0, c0+1)
    const float* p10 = p00 + RS_IN;      // (r0+1, c0)
    const float* p11 = p00 + RS_IN + IN_N;

    float* resw = &res[wave * 64 * 32];
    float* yb = y + (size_t)bh * BH_OUT;

    // d-chunk windows (chunk ch covers dd in [32ch, 32ch+32)); all compile-time
    constexpr int WBASE[3] = {0, 12, 28};
    constexpr int NW[3]    = {5, 6, 5};

    #pragma unroll
    for (int ch = 0; ch < 3; ++ch) {
        // rc-blended input line segment for this chunk
        float f[24];
        #pragma unroll
        for (int wj = 0; wj < 6; ++wj) {
            if (wj < NW[ch]) {
                const int off = WBASE[ch] + 4 * wj;
                float4 va = *reinterpret_cast<const float4*>(p00 + off);
                float4 vb = *reinterpret_cast<const float4*>(p01 + off);
                float4 vc = *reinterpret_cast<const float4*>(p10 + off);
                float4 vd = *reinterpret_cast<const float4*>(p11 + off);
                f[4*wj+0] = w00*va.x + w01*vb.x + w10*vc.x + w11*vd.x;
                f[4*wj+1] = w00*va.y + w01*vb.y + w10*vc.y + w11*vd.y;
                f[4*wj+2] = w00*va.z + w01*vb.z + w10*vc.z + w11*vd.z;
                f[4*wj+3] = w00*va.w + w01*vb.w + w10*vc.w + w11*vd.w;
            }
        }

        // d-blend (compile-time indices/weights) + wave-local res write
        #pragma unroll
        for (int q = 0; q < 8; ++q) {
            float vv[4];
            #pragma unroll
            for (int i = 0; i < 4; ++i) {
                const int dd = ch * 32 + 4 * q + i;
                const int j0 = (47 * dd) / 95 - WBASE[ch];
                const float fd1 = (float)((47 * dd) % 95) * (1.0f / 95.0f);
                vv[i] = (1.0f - fd1) * f[j0] + fd1 * f[j0 + 1];
            }
            float4 v = make_float4(vv[0], vv[1], vv[2], vv[3]);
            *reinterpret_cast<float4*>(&resw[(lane << 5) + ((q ^ (lane & 7)) << 2)]) = v;
        }

        __builtin_amdgcn_wave_barrier();   // keep write->read order (wave-synchronous)

        // coalesced store: wave covers rows 4*wave..4*wave+3, cols 0..15, this chunk
        #pragma unroll
        for (int it = 0; it < 8; ++it) {
            const int idx = it * 64 + lane;
            const int k  = idx & 7;
            const int cc = (idx >> 3) & 15;
            const int rr = idx >> 7;
            const int rc = (rr << 4) + cc;
            float4 v = *reinterpret_cast<const float4*>(&resw[(rc << 5) + ((k ^ (rc & 7)) << 2)]);
            *reinterpret_cast<float4*>(
                &yb[(size_t)(br * 16 + (wave << 2) + rr) * RS_OUT
                    + (bc * 16 + cc) * OUT_N + ch * 32 + (k << 2)]) = v;
        }

        __builtin_amdgcn_wave_barrier();   // WAR: next chunk rewrites resw
    }
}

extern "C" void kernel_launch(void* const* d_in, const int* in_sizes, int n_in,
                              void* d_out, int out_size, void* d_ws, size_t ws_size,
                              hipStream_t stream) {
    const float* x = (const float*)d_in[0];
    float* y = (float*)d_out;
    dim3 grid(OUT_N / 16, OUT_N / 16, 64);   // 6 x 6 x 64 = 2304 blocks
    hipLaunchKernelGGL(up3d_kernel, grid, dim3(256), 0, stream, x, y);
}

// Round 7
// 241.171 us; speedup vs baseline: 1.1936x; 1.1936x over previous
//
#include <hip/hip_runtime.h>

// UpSampling3D x2 trilinear, align_corners=True.
// x [64,48,48,48] f32 -> y [64,96,96,96] f32
// pos(o) = 47*o/95; weights (1-fr, fr) at (floor, floor+1); norm (1/(1+1e-6))^3
// (norm^3 folded into the r-blend stage weights; all axes linear => exact).
//
// R6: one block per output plane (bh, r_out).
//  - stage: coalesced float4 loads of input planes r0,r0+1; r-blend into
//    LDS P[48][52] (9.8 KB -> 8 blocks/CU); ONE barrier.
//  - compute: thread -> linear (c, d-group of 4); 8 ds_read_b32 (2-way max),
//    c-blend then select-based d-blend (static reg indices); contiguous
//    float4 stores (wave = 1KB).
//  - bijective XCD-chunked swizzle: each XCD works 8 bh-slices -> plane
//    re-reads (~4x) hit its private L2.

#define IN_N      48
#define RS_IN     (48*48)      // 2304
#define BH_IN     (48*48*48)   // 110592
#define OUT_N     96
#define PLANE_OUT (96*96)      // 9216
#define PADW      52           // padded LDS row width (16B-aligned, odd*4 bank spread)

__global__ __launch_bounds__(256, 8) void up3d_kernel(const float* __restrict__ x,
                                                      float* __restrict__ y) {
    __shared__ float P[IN_N * PADW];   // 9984 B

    const int tid = threadIdx.x;
    // XCD-chunked bijective swizzle: 6144 blocks = 8 XCDs x 768
    const int fid = blockIdx.x;
    const int swz = (fid & 7) * 768 + (fid >> 3);
    const int r_out = swz % 96;
    const int bh    = swz / 96;

    const int t47 = 47 * r_out;
    const int r0  = t47 / 95;
    const int r1  = min(r0 + 1, IN_N - 1);          // r_out=95 -> fr=0, clamp safe
    const float fr = (float)(t47 - 95 * r0) * (1.0f / 95.0f);
    const float n1 = 1.0f / (1.0f + 1e-6f);
    const float n3 = n1 * n1 * n1;
    const float wa = (1.0f - fr) * n3;
    const float wb = fr * n3;

    const float* pA = x + (size_t)bh * BH_IN + (size_t)r0 * RS_IN;
    const float* pB = x + (size_t)bh * BH_IN + (size_t)r1 * RS_IN;

    // ---- stage: r-blended plane -> LDS (coalesced float4 global reads) ----
    for (int i = tid; i < 576; i += 256) {          // 576 float4 = 48x48 plane
        const int c = i / 12, k = i % 12;
        float4 a = *reinterpret_cast<const float4*>(pA + c * IN_N + 4 * k);
        float4 b = *reinterpret_cast<const float4*>(pB + c * IN_N + 4 * k);
        float4 v;
        v.x = wa * a.x + wb * b.x;
        v.y = wa * a.y + wb * b.y;
        v.z = wa * a.z + wb * b.z;
        v.w = wa * a.w + wb * b.w;
        *reinterpret_cast<float4*>(&P[c * PADW + 4 * k]) = v;
    }
    if (tid < IN_N) {                                // zero pad cols 48..51 (window overrun, weight 0)
        *reinterpret_cast<float4*>(&P[tid * PADW + 48]) = make_float4(0.f, 0.f, 0.f, 0.f);
    }
    __syncthreads();

    float* yb = y + (size_t)swz * PLANE_OUT;         // swz == bh*96 + r_out

    #pragma unroll
    for (int it = 0; it < 9; ++it) {                 // 9*256 = 2304 float4 = full plane
        const int idx = it * 256 + tid;
        const int dg = idx % 24;                     // d-group (4 outputs along d)
        const int c  = idx / 24;                     // output col 0..95

        const int tc = 47 * c;
        const int c0 = tc / 95;
        const int c1 = min(c0 + 1, IN_N - 1);
        const float wc1 = (float)(tc - 95 * c0) * (1.0f / 95.0f);
        const float wc0 = 1.0f - wc1;

        const int td  = 188 * dg;                    // 47*(4*dg)
        const int dlo = td / 95;                     // window start (covers d0..d0+1 of all 4 d)
        const int rm0 = td - 95 * dlo;

        const float* rowA = &P[c0 * PADW + dlo];
        const float* rowB = &P[c1 * PADW + dlo];
        const float f0 = wc0 * rowA[0] + wc1 * rowB[0];
        const float f1 = wc0 * rowA[1] + wc1 * rowB[1];
        const float f2 = wc0 * rowA[2] + wc1 * rowB[2];
        const float f3 = wc0 * rowA[3] + wc1 * rowB[3];

        float4 o;
        float* op = reinterpret_cast<float*>(&o);
        #pragma unroll
        for (int i = 0; i < 4; ++i) {
            const int s = rm0 + 47 * i;              // 95*delta + rem
            const int delta = (s >= 95 ? 1 : 0) + (s >= 190 ? 1 : 0);   // 0..2
            const float fd1 = (float)(s - 95 * delta) * (1.0f / 95.0f);
            const float lo = (delta == 0) ? f0 : ((delta == 1) ? f1 : f2);
            const float hi = (delta == 0) ? f1 : ((delta == 1) ? f2 : f3);
            op[i] = lo + fd1 * (hi - lo);
        }
        *reinterpret_cast<float4*>(yb + 4 * idx) = o;   // fully contiguous per block
    }
}

extern "C" void kernel_launch(void* const* d_in, const int* in_sizes, int n_in,
                              void* d_out, int out_size, void* d_ws, size_t ws_size,
                              hipStream_t stream) {
    const float* x = (const float*)d_in[0];
    float* y = (float*)d_out;
    hipLaunchKernelGGL(up3d_kernel, dim3(64 * 96), dim3(256), 0, stream, x, y);
}